// Round 4
// baseline (282.348 us; speedup 1.0000x reference)
//
#include <hip/hip_runtime.h>

#define BATCH 2
#define SS    256   // 16x16 subdomain grid
#define CC    128
#define HWN   256   // 16x16 spatial
#define NHEAD 8
#define FDIM  4096  // 64 ch * 8 * 8 per head

typedef unsigned int uint;
typedef unsigned short ushort;
typedef short bf16x8 __attribute__((ext_vector_type(8)));
typedef ushort us4 __attribute__((ext_vector_type(4)));
typedef float f32x4 __attribute__((ext_vector_type(4)));

__device__ __forceinline__ ushort f2b(float f) {
  uint u = __float_as_uint(f);
  return (ushort)((u + 0x7fffu + ((u >> 16) & 1u)) >> 16);  // RNE
}
__device__ __forceinline__ float b2f(ushort h) { return __uint_as_float((uint)h << 16); }

// ---------------- K0: convert weights to bf16 ----------------
__global__ void k_convert(const float* __restrict__ wqkv, const float* __restrict__ wout,
                          ushort* __restrict__ wqkv_b, ushort* __restrict__ wout_b) {
  int i = blockIdx.x * 256 + threadIdx.x;
  if (i < 384 * 128) wqkv_b[i] = f2b(wqkv[i]);
  if (i < 128 * 128) wout_b[i] = f2b(wout[i]);
}

// ---------------- K1: qkv projection + head scatter ----------------
// Grid: 512 bs x 4 hq, 256 threads (4 waves, 1 ntg each) -> 32 waves/CU.
// Double-buffered wqkv afrag prefetch across the unrolled mt loop.
// q,k layout: qkvh[(qkvi*16+b*8+n)][s][f], f = hwl*64 + c
// v   layout: f_v = (c>>5)*2048 + hwl*32 + ((c>>3)&3)*8 + (c&7)
__global__ __launch_bounds__(256) void k_qkv(const float* __restrict__ seq,
                                             const ushort* __restrict__ wqkv_b,
                                             ushort* __restrict__ qkvh) {
  const int blk = blockIdx.x;
  const int bs = blk >> 2, hq = blk & 3;
  const int b = bs >> 8, s = bs & 255;
  const int t = threadIdx.x;
  const int wave = t >> 6, lane = t & 63;
  const int qq = lane >> 4, m = lane & 15;
  const int ntg = hq * 4 + wave;          // this wave's hw row (0..15)
  const int hw = ntg * 16 + m;

  const float* sp = seq + (size_t)bs * (CC * HWN);

  // B fragment: bfrag[ks] elem j = bf16(seq[k=ks*32+qq*8+j][hw])
  bf16x8 bfrag[4];
  #pragma unroll
  for (int ks = 0; ks < 4; ++ks) {
    const int k0 = ks * 32 + qq * 8;
    float tmp[8];
    #pragma unroll
    for (int j = 0; j < 8; ++j) tmp[j] = sp[(k0 + j) * HWN + hw];
    bf16x8 fr;
    #pragma unroll
    for (int j = 0; j < 8; ++j) fr[j] = (short)f2b(tmp[j]);
    bfrag[ks] = fr;
  }

  const int n_qk = ((ntg >> 3) * 2 + (m >> 3)) * 2;     // head base (+ch)
  const int hwl  = (ntg & 7) * 8 + (m & 7);             // local spatial idx

  bf16x8 af[2][4];
  #pragma unroll
  for (int ks = 0; ks < 4; ++ks)
    af[0][ks] = *(const bf16x8*)(wqkv_b + m * CC + ks * 32 + qq * 8);

  #pragma unroll
  for (int mt = 0; mt < 24; ++mt) {
    const int cur = mt & 1;
    if (mt < 23) {
      const ushort* ap = wqkv_b + ((mt + 1) * 16 + m) * CC;
      #pragma unroll
      for (int ks = 0; ks < 4; ++ks)
        af[cur ^ 1][ks] = *(const bf16x8*)(ap + ks * 32 + qq * 8);
    }
    f32x4 acc = {0.f, 0.f, 0.f, 0.f};
    #pragma unroll
    for (int ks = 0; ks < 4; ++ks)
      acc = __builtin_amdgcn_mfma_f32_16x16x32_bf16(af[cur][ks], bfrag[ks], acc, 0, 0, 0);
    const int qkvi = mt >> 3, mt8 = mt & 7;
    const int ch = (mt8 >> 2) & 1;
    const int m4 = mt8 & 3;
    const int n = n_qk + ch;
    const size_t base = ((size_t)(qkvi * 16 + b * 8 + n) * SS + s) * FDIM;
    us4 pk;
    #pragma unroll
    for (int r = 0; r < 4; ++r) pk[r] = f2b(acc[r]);
    if (qkvi < 2) {
      *(us4*)(qkvh + base + hwl * 64 + m4 * 16 + qq * 4) = pk;
    } else {
      const int fv = (m4 >> 1) * 2048 + hwl * 32 + ((m4 & 1) * 2 + (qq >> 1)) * 8 + (qq & 1) * 4;
      *(us4*)(qkvh + base + fv) = pk;
    }
  }
}

// ---------------- K2: MFMA scores + softmax -> <=9 weights per (b,n,s) -------
// Block = (b,n,sy); 8 waves split K into 512-chunks (unroll 2 -> 8 loads in flight).
__global__ __launch_bounds__(512) void k_scores(const ushort* __restrict__ qkvh,
                                                float* __restrict__ attn) {
  const int unit = blockIdx.x;            // (b,n,sy)
  const int b  = unit >> 7;
  const int n  = (unit >> 4) & 7;
  const int sy = unit & 15;
  const int t = threadIdx.x;
  const int wave = t >> 6, lane = t & 63;
  const int qq = lane >> 4, l15 = lane & 15;
  const size_t hs = (size_t)SS * FDIM;
  const ushort* qb = qkvh + (size_t)(b * 8 + n) * hs;
  const ushort* kb = qkvh + (size_t)(16 + b * 8 + n) * hs;

  const ushort* qp = qb + (size_t)(sy * 16 + l15) * FDIM + qq * 8;
  const ushort* kp[3];
  #pragma unroll
  for (int tl = 0; tl < 3; ++tl) {
    const int tyc = min(max(sy - 1 + tl, 0), 15);
    kp[tl] = kb + (size_t)(tyc * 16 + l15) * FDIM + qq * 8;
  }

  f32x4 acc[3] = {{0,0,0,0},{0,0,0,0},{0,0,0,0}};
  const int kbeg = wave * 512, kend = kbeg + 512;
  for (int k0 = kbeg; k0 < kend; k0 += 64) {
    bf16x8 a0 = *(const bf16x8*)(qp + k0);
    bf16x8 a1 = *(const bf16x8*)(qp + k0 + 32);
    bf16x8 b0[3], b1[3];
    #pragma unroll
    for (int tl = 0; tl < 3; ++tl) {
      b0[tl] = *(const bf16x8*)(kp[tl] + k0);
      b1[tl] = *(const bf16x8*)(kp[tl] + k0 + 32);
    }
    #pragma unroll
    for (int tl = 0; tl < 3; ++tl)
      acc[tl] = __builtin_amdgcn_mfma_f32_16x16x32_bf16(a0, b0[tl], acc[tl], 0, 0, 0);
    #pragma unroll
    for (int tl = 0; tl < 3; ++tl)
      acc[tl] = __builtin_amdgcn_mfma_f32_16x16x32_bf16(a1, b1[tl], acc[tl], 0, 0, 0);
  }

  // cross-wave reduce: waves 1..7 dump partials, wave 0 sums
  __shared__ float red[7][64][12];
  if (wave > 0) {
    #pragma unroll
    for (int tl = 0; tl < 3; ++tl)
      #pragma unroll
      for (int r = 0; r < 4; ++r) red[wave - 1][lane][tl * 4 + r] = acc[tl][r];
  }
  __syncthreads();
  if (wave != 0) return;
  #pragma unroll
  for (int w = 0; w < 7; ++w)
    #pragma unroll
    for (int tl = 0; tl < 3; ++tl)
      #pragma unroll
      for (int r = 0; r < 4; ++r) acc[tl][r] += red[w][lane][tl * 4 + r];

  // mask + softmax.  D layout: row sx = qq*4+r, col tx = l15.
  const int tx = l15;
  float sc[3][4];
  #pragma unroll
  for (int tl = 0; tl < 3; ++tl) {
    const int ty = sy - 1 + tl;
    const bool tyv = (ty >= 0 && ty < 16);
    #pragma unroll
    for (int r = 0; r < 4; ++r) {
      const int sx = qq * 4 + r;
      const bool v = tyv && (tx - sx <= 1) && (sx - tx <= 1);
      sc[tl][r] = v ? acc[tl][r] * (1.f / 64.f) : -1e30f;
    }
  }
  #pragma unroll
  for (int r = 0; r < 4; ++r) {
    float mx = fmaxf(fmaxf(sc[0][r], sc[1][r]), sc[2][r]);
    #pragma unroll
    for (int off = 1; off < 16; off <<= 1) mx = fmaxf(mx, __shfl_xor(mx, off));
    float p[3], sum = 0.f;
    #pragma unroll
    for (int tl = 0; tl < 3; ++tl) { p[tl] = __expf(sc[tl][r] - mx); sum += p[tl]; }
    #pragma unroll
    for (int off = 1; off < 16; off <<= 1) sum += __shfl_xor(sum, off);
    const float inv = 1.f / sum;
    const int sx = qq * 4 + r;
    const int s = sy * 16 + sx;
    #pragma unroll
    for (int tl = 0; tl < 3; ++tl) {
      const int ty = sy - 1 + tl;
      const int dxp = tx - sx + 1;
      if (ty >= 0 && ty < 16 && dxp >= 0 && dxp <= 2)
        attn[((size_t)(b * 8 + n) * SS + s) * 9 + tl * 3 + dxp] = p[tl] * inv;
    }
  }
}

// ---------------- K3: PV (dense v loads, prefetched) + out projection --------
__global__ __launch_bounds__(256) void k_out(const ushort* __restrict__ qkvh,
                                             const float* __restrict__ attn,
                                             const ushort* __restrict__ wout_b,
                                             const float* __restrict__ bout,
                                             float* __restrict__ out) {
  const int blk = blockIdx.x;
  const int bs = blk >> 2, sub = blk & 3;
  const int b = bs >> 8, s = bs & 255;
  const int t = threadIdx.x;
  const int wave = t >> 6, lane = t & 63;
  const int ntg = sub * 4 + wave;
  const int qq = lane >> 4, m = lane & 15;
  const int sy = s >> 4, sx = s & 15;
  const size_t hs = (size_t)SS * FDIM;

  int sjc[9];
  bool vld[9];
  #pragma unroll
  for (int j = 0; j < 9; ++j) {
    const int ny = sy + j / 3 - 1, nx = sx + j % 3 - 1;
    vld[j] = (ny >= 0 && ny < 16 && nx >= 0 && nx < 16);
    sjc[j] = min(max(ny, 0), 15) * 16 + min(max(nx, 0), 15);
  }

  const int yh = ntg >> 3;
  const int nbase = (yh * 2 + (m >> 3)) * 2;  // + ch
  float pch[2][9];
  #pragma unroll
  for (int ch = 0; ch < 2; ++ch) {
    #pragma unroll
    for (int j = 0; j < 9; ++j) {
      const float w = attn[((size_t)(b * 8 + nbase + ch) * SS + s) * 9 + j];
      pch[ch][j] = vld[j] ? w : 0.f;
    }
  }

  // sa in MFMA B-fragment layout; v loads double-buffered across ks stages
  const int hwl = (ntg & 7) * 8 + (m & 7);
  const ushort* vb0 = qkvh + (size_t)(32 + b * 8 + nbase) * hs;      // ch=0
  const ushort* vb1 = qkvh + (size_t)(32 + b * 8 + nbase + 1) * hs;  // ch=1
  const int fvl = hwl * 32 + qq * 8;

  bf16x8 vbuf[2][9];
  #pragma unroll
  for (int j = 0; j < 9; ++j)
    vbuf[0][j] = *(const bf16x8*)(vb0 + (size_t)sjc[j] * FDIM + fvl);

  bf16x8 bfrag[4];
  #pragma unroll
  for (int ks = 0; ks < 4; ++ks) {
    const int cur = ks & 1;
    if (ks < 3) {
      const int ksn = ks + 1;
      const ushort* vbn = (ksn >> 1) ? vb1 : vb0;
      const int fvn = (ksn & 1) * 2048 + fvl;
      #pragma unroll
      for (int j = 0; j < 9; ++j)
        vbuf[cur ^ 1][j] = *(const bf16x8*)(vbn + (size_t)sjc[j] * FDIM + fvn);
    }
    const int ch = ks >> 1;
    float facc[8] = {0.f, 0.f, 0.f, 0.f, 0.f, 0.f, 0.f, 0.f};
    #pragma unroll
    for (int j = 0; j < 9; ++j) {
      const float pj = pch[ch][j];
      #pragma unroll
      for (int e = 0; e < 8; ++e) facc[e] += pj * b2f((ushort)vbuf[cur][j][e]);
    }
    bf16x8 fr;
    #pragma unroll
    for (int e = 0; e < 8; ++e) fr[e] = (short)f2b(facc[e]);
    bfrag[ks] = fr;
  }

  // out[d][hw] = wout[d][cc] @ sa[cc][hw] + bout[d], wout afrags double-buffered
  bf16x8 wa[2][4];
  #pragma unroll
  for (int ks = 0; ks < 4; ++ks)
    wa[0][ks] = *(const bf16x8*)(wout_b + m * CC + ks * 32 + qq * 8);

  #pragma unroll
  for (int mt = 0; mt < 8; ++mt) {
    const int cur = mt & 1;
    if (mt < 7) {
      const ushort* ap = wout_b + ((mt + 1) * 16 + m) * CC;
      #pragma unroll
      for (int ks = 0; ks < 4; ++ks)
        wa[cur ^ 1][ks] = *(const bf16x8*)(ap + ks * 32 + qq * 8);
    }
    f32x4 acc = {0.f, 0.f, 0.f, 0.f};
    #pragma unroll
    for (int ks = 0; ks < 4; ++ks)
      acc = __builtin_amdgcn_mfma_f32_16x16x32_bf16(wa[cur][ks], bfrag[ks], acc, 0, 0, 0);
    const int hw = ntg * 16 + m;
    #pragma unroll
    for (int r = 0; r < 4; ++r) {
      const int d = mt * 16 + qq * 4 + r;
      out[((size_t)bs * CC + d) * HWN + hw] = acc[r] + bout[d];
    }
  }
}

extern "C" void kernel_launch(void* const* d_in, const int* in_sizes, int n_in,
                              void* d_out, int out_size, void* d_ws, size_t ws_size,
                              hipStream_t stream) {
  const float* seq  = (const float*)d_in[0];
  const float* wqkv = (const float*)d_in[1];
  const float* wout = (const float*)d_in[2];
  const float* bout = (const float*)d_in[3];
  char* ws = (char*)d_ws;
  // ws layout (bytes): wqkv_b 98304 | wout_b 32768 | qkvh 100663296 | attn 147456
  ushort* wqkv_b = (ushort*)(ws);
  ushort* wout_b = (ushort*)(ws + 98304);
  ushort* qkvh   = (ushort*)(ws + 131072);
  float*  attn   = (float*)(ws + 131072 + 100663296ull);
  float*  outp   = (float*)d_out;

  hipLaunchKernelGGL(k_convert, dim3(192),  dim3(256), 0, stream, wqkv, wout, wqkv_b, wout_b);
  hipLaunchKernelGGL(k_qkv,     dim3(2048), dim3(256), 0, stream, seq, wqkv_b, qkvh);
  hipLaunchKernelGGL(k_scores,  dim3(256),  dim3(512), 0, stream, qkvh, attn);
  hipLaunchKernelGGL(k_out,     dim3(2048), dim3(256), 0, stream, qkvh, attn, wout_b, bout, outp);
}

// Round 5
// 212.915 us; speedup vs baseline: 1.3261x; 1.3261x over previous
//
#include <hip/hip_runtime.h>

#define BATCH 2
#define SS    256   // 16x16 subdomain grid
#define CC    128
#define HWN   256   // 16x16 spatial
#define FDIM  4096  // 64 ch * 8 * 8 per head

typedef unsigned int uint;
typedef unsigned short ushort;
typedef short bf16x8 __attribute__((ext_vector_type(8)));
typedef ushort us4 __attribute__((ext_vector_type(4)));
typedef float f32x4 __attribute__((ext_vector_type(4)));

__device__ __forceinline__ ushort f2b(float f) {
  uint u = __float_as_uint(f);
  return (ushort)((u + 0x7fffu + ((u >> 16) & 1u)) >> 16);  // RNE
}
__device__ __forceinline__ float b2f(ushort h) { return __uint_as_float((uint)h << 16); }

// ---------------- K0: convert weights to bf16 (wout permuted to cc' order) ---
// cc' = ks*32 + qq*8 + j  <->  c_real = (ks>>1)*64 + ((((ks&1)<<1)|(qq>>1))<<4)
//                                        + ((qq&1)<<3) + j
__global__ void k_convert(const float* __restrict__ wqkv, const float* __restrict__ wout,
                          ushort* __restrict__ wqkv_b, ushort* __restrict__ wout_b) {
  int i = blockIdx.x * 256 + threadIdx.x;
  if (i < 384 * 128) wqkv_b[i] = f2b(wqkv[i]);
  if (i < 128 * 128) {
    const int cc = i & 127;
    const int ks = cc >> 5, qq = (cc >> 3) & 3, j = cc & 7;
    const int creal = (ks >> 1) * 64 + ((((ks & 1) << 1) | (qq >> 1)) << 4)
                      + ((qq & 1) << 3) + j;
    wout_b[i] = f2b(wout[(i >> 7) * 128 + creal]);
  }
}

// ---------------- K1: qkv projection + head scatter ----------------
// Grid: 3 qkvi x 512 bs, 256 threads (4 waves x 4 ntp). Weights slice in LDS.
// Unified layout: qkvh[(qkvi*16+b*8+n)][s][f'], f' = (c>>4)*1024 + hwl*16 + (c&15)
// -> each store inst = 2 x 256 B contiguous segments.
__global__ __launch_bounds__(256) void k_qkv(const float* __restrict__ seq,
                                             const ushort* __restrict__ wqkv_b,
                                             ushort* __restrict__ qkvh) {
  __shared__ ushort wlds[128 * 128];   // 32 KB, XOR-swizzled 16-B blocks
  const int blk = blockIdx.x;
  const int qkvi = blk >> 9, bs = blk & 511;
  const int b = bs >> 8, s = bs & 255;
  const int t = threadIdx.x;
  const int wave = t >> 6, lane = t & 63;
  const int qq = lane >> 4, m = lane & 15;

  const float* sp = seq + (size_t)bs * (CC * HWN);

  // B fragments: bfrag[ntp][ks] elem j = bf16(seq[c=ks*32+qq*8+j][hw=(wave*4+ntp)*16+m])
  bf16x8 bfrag[4][4];
  #pragma unroll
  for (int ntp = 0; ntp < 4; ++ntp) {
    const int hw = (wave * 4 + ntp) * 16 + m;
    #pragma unroll
    for (int ks = 0; ks < 4; ++ks) {
      const int k0 = ks * 32 + qq * 8;
      float tmp[8];
      #pragma unroll
      for (int j = 0; j < 8; ++j) tmp[j] = sp[(k0 + j) * HWN + hw];
      bf16x8 fr;
      #pragma unroll
      for (int j = 0; j < 8; ++j) fr[j] = (short)f2b(tmp[j]);
      bfrag[ntp][ks] = fr;
    }
  }

  // Stage this qkvi's 128x128 weight slice into LDS, coalesced.
  // LDS addr(row, col16) = row*128 + (col16 ^ (row&15))*8   (ushort units)
  #pragma unroll
  for (int i = 0; i < 8; ++i) {
    const int row = i * 16 + (t >> 4), col16 = t & 15;
    bf16x8 w = *(const bf16x8*)(wqkv_b + (qkvi * 128 + row) * 128 + col16 * 8);
    *(bf16x8*)&wlds[row * 128 + ((col16 ^ (row & 15)) * 8)] = w;
  }
  __syncthreads();

  #pragma unroll
  for (int mt8 = 0; mt8 < 8; ++mt8) {
    bf16x8 afrag[4];
    #pragma unroll
    for (int ks = 0; ks < 4; ++ks)
      afrag[ks] = *(const bf16x8*)&wlds[(mt8 * 16 + m) * 128 + (((ks * 4 + qq) ^ m) * 8)];
    const int ch = mt8 >> 2, m4 = mt8 & 3;
    #pragma unroll
    for (int ntp = 0; ntp < 4; ++ntp) {
      f32x4 acc = {0.f, 0.f, 0.f, 0.f};
      #pragma unroll
      for (int ks = 0; ks < 4; ++ks)
        acc = __builtin_amdgcn_mfma_f32_16x16x32_bf16(afrag[ks], bfrag[ntp][ks], acc, 0, 0, 0);
      const int ntg = wave * 4 + ntp;                       // hw row (y)
      const int n   = ((ntg >> 3) * 2 + (m >> 3)) * 2 + ch; // head
      const int hwl = (ntg & 7) * 8 + (m & 7);              // local spatial idx
      const size_t base = ((size_t)(qkvi * 16 + b * 8 + n) * SS + s) * FDIM;
      us4 pk;
      #pragma unroll
      for (int r = 0; r < 4; ++r) pk[r] = f2b(acc[r]);
      *(us4*)(qkvh + base + m4 * 1024 + hwl * 16 + qq * 4) = pk;
    }
  }
}

// ---------------- K2: MFMA scores + softmax -> <=9 weights per (b,n,s) -------
// Block = (b,n,sy); 16 waves split K (4096) into 256-chunks; LDS tree reduce.
__global__ __launch_bounds__(1024) void k_scores(const ushort* __restrict__ qkvh,
                                                 float* __restrict__ attn) {
  __shared__ float red[16][64][12];
  const int unit = blockIdx.x;            // (b,n,sy)
  const int b  = unit >> 7;
  const int n  = (unit >> 4) & 7;
  const int sy = unit & 15;
  const int t = threadIdx.x;
  const int wave = t >> 6, lane = t & 63;
  const int qq = lane >> 4, l15 = lane & 15;
  const size_t hs = (size_t)SS * FDIM;
  const ushort* qb = qkvh + (size_t)(b * 8 + n) * hs;
  const ushort* kb = qkvh + (size_t)(16 + b * 8 + n) * hs;

  const ushort* qp = qb + (size_t)(sy * 16 + l15) * FDIM + qq * 8;
  const ushort* kp[3];
  #pragma unroll
  for (int tl = 0; tl < 3; ++tl) {
    const int tyc = min(max(sy - 1 + tl, 0), 15);
    kp[tl] = kb + (size_t)(tyc * 16 + l15) * FDIM + qq * 8;
  }

  f32x4 acc[3] = {{0,0,0,0},{0,0,0,0},{0,0,0,0}};
  const int kbeg = wave * 256;
  #pragma unroll
  for (int it = 0; it < 4; ++it) {
    const int k0 = kbeg + it * 64;
    bf16x8 a0 = *(const bf16x8*)(qp + k0);
    bf16x8 a1 = *(const bf16x8*)(qp + k0 + 32);
    bf16x8 b0[3], b1[3];
    #pragma unroll
    for (int tl = 0; tl < 3; ++tl) {
      b0[tl] = *(const bf16x8*)(kp[tl] + k0);
      b1[tl] = *(const bf16x8*)(kp[tl] + k0 + 32);
    }
    #pragma unroll
    for (int tl = 0; tl < 3; ++tl)
      acc[tl] = __builtin_amdgcn_mfma_f32_16x16x32_bf16(a0, b0[tl], acc[tl], 0, 0, 0);
    #pragma unroll
    for (int tl = 0; tl < 3; ++tl)
      acc[tl] = __builtin_amdgcn_mfma_f32_16x16x32_bf16(a1, b1[tl], acc[tl], 0, 0, 0);
  }

  #pragma unroll
  for (int tl = 0; tl < 3; ++tl)
    #pragma unroll
    for (int r = 0; r < 4; ++r) red[wave][lane][tl * 4 + r] = acc[tl][r];
  __syncthreads();
  if (t < 768) {
    const int lane2 = t / 12, idx = t - lane2 * 12;
    float ssum = red[0][lane2][idx];
    #pragma unroll
    for (int w = 1; w < 16; ++w) ssum += red[w][lane2][idx];
    red[0][lane2][idx] = ssum;
  }
  __syncthreads();
  if (wave != 0) return;
  #pragma unroll
  for (int tl = 0; tl < 3; ++tl)
    #pragma unroll
    for (int r = 0; r < 4; ++r) acc[tl][r] = red[0][lane][tl * 4 + r];

  // mask + softmax.  D layout: row sx = qq*4+r, col tx = l15.
  const int tx = l15;
  float sc[3][4];
  #pragma unroll
  for (int tl = 0; tl < 3; ++tl) {
    const int ty = sy - 1 + tl;
    const bool tyv = (ty >= 0 && ty < 16);
    #pragma unroll
    for (int r = 0; r < 4; ++r) {
      const int sx = qq * 4 + r;
      const bool v = tyv && (tx - sx <= 1) && (sx - tx <= 1);
      sc[tl][r] = v ? acc[tl][r] * (1.f / 64.f) : -1e30f;
    }
  }
  #pragma unroll
  for (int r = 0; r < 4; ++r) {
    float mx = fmaxf(fmaxf(sc[0][r], sc[1][r]), sc[2][r]);
    #pragma unroll
    for (int off = 1; off < 16; off <<= 1) mx = fmaxf(mx, __shfl_xor(mx, off));
    float p[3], sum = 0.f;
    #pragma unroll
    for (int tl = 0; tl < 3; ++tl) { p[tl] = __expf(sc[tl][r] - mx); sum += p[tl]; }
    #pragma unroll
    for (int off = 1; off < 16; off <<= 1) sum += __shfl_xor(sum, off);
    const float inv = 1.f / sum;
    const int sx = qq * 4 + r;
    const int s = sy * 16 + sx;
    #pragma unroll
    for (int tl = 0; tl < 3; ++tl) {
      const int ty = sy - 1 + tl;
      const int dxp = tx - sx + 1;
      if (ty >= 0 && ty < 16 && dxp >= 0 && dxp <= 2)
        attn[((size_t)(b * 8 + n) * SS + s) * 9 + tl * 3 + dxp] = p[tl] * inv;
    }
  }
}

// ---------------- K3: PV (256-B-segment v loads) + out projection ------------
// Grid: 512 bs x 4 sub; wave handles ntg = sub*4 + wave. wout_perm in LDS.
__global__ __launch_bounds__(256) void k_out(const ushort* __restrict__ qkvh,
                                             const float* __restrict__ attn,
                                             const ushort* __restrict__ wout_b,
                                             const float* __restrict__ bout,
                                             float* __restrict__ out) {
  __shared__ ushort wlds[128 * 128];   // 32 KB, XOR-swizzled
  const int blk = blockIdx.x;
  const int bs = blk >> 2, sub = blk & 3;
  const int b = bs >> 8, s = bs & 255;
  const int t = threadIdx.x;
  const int wave = t >> 6, lane = t & 63;
  const int ntg = sub * 4 + wave;
  const int qq = lane >> 4, m = lane & 15;
  const int sy = s >> 4, sx = s & 15;
  const size_t hs = (size_t)SS * FDIM;

  // Stage permuted wout into LDS, coalesced.
  #pragma unroll
  for (int i = 0; i < 8; ++i) {
    const int row = i * 16 + (t >> 4), col16 = t & 15;
    bf16x8 w = *(const bf16x8*)(wout_b + row * 128 + col16 * 8);
    *(bf16x8*)&wlds[row * 128 + ((col16 ^ (row & 15)) * 8)] = w;
  }

  int sjc[9];
  bool vld[9];
  #pragma unroll
  for (int j = 0; j < 9; ++j) {
    const int ny = sy + j / 3 - 1, nx = sx + j % 3 - 1;
    vld[j] = (ny >= 0 && ny < 16 && nx >= 0 && nx < 16);
    sjc[j] = min(max(ny, 0), 15) * 16 + min(max(nx, 0), 15);
  }

  const int nbase = ((ntg >> 3) * 2 + (m >> 3)) * 2;  // + ch
  float pch[2][9];
  #pragma unroll
  for (int ch = 0; ch < 2; ++ch) {
    #pragma unroll
    for (int j = 0; j < 9; ++j) {
      const float w = attn[((size_t)(b * 8 + nbase + ch) * SS + s) * 9 + j];
      pch[ch][j] = vld[j] ? w : 0.f;
    }
  }

  // sa in MFMA B-fragment layout; unified v layout -> 4 x 256-B segments/load
  const int hwl = (ntg & 7) * 8 + (m & 7);
  bf16x8 bfrag[4];
  #pragma unroll
  for (int ks = 0; ks < 4; ++ks) {
    const int ch = ks >> 1;
    const int c64hi = ((ks & 1) << 1) | (qq >> 1);
    const int half = qq & 1;
    const ushort* vb = qkvh + (size_t)(32 + b * 8 + nbase + ch) * hs;
    const int off = c64hi * 1024 + hwl * 16 + half * 8;
    float facc[8] = {0.f, 0.f, 0.f, 0.f, 0.f, 0.f, 0.f, 0.f};
    #pragma unroll
    for (int j = 0; j < 9; ++j) {
      bf16x8 vv = *(const bf16x8*)(vb + (size_t)sjc[j] * FDIM + off);
      const float pj = pch[ch][j];
      #pragma unroll
      for (int e = 0; e < 8; ++e) facc[e] += pj * b2f((ushort)vv[e]);
    }
    bf16x8 fr;
    #pragma unroll
    for (int e = 0; e < 8; ++e) fr[e] = (short)f2b(facc[e]);
    bfrag[ks] = fr;
  }

  __syncthreads();   // staging complete before afrag reads

  // out[d][hw] = wout_perm[d][cc'] @ sa[cc'][hw] + bout[d]
  #pragma unroll
  for (int mt = 0; mt < 8; ++mt) {
    bf16x8 afrag[4];
    #pragma unroll
    for (int ks = 0; ks < 4; ++ks)
      afrag[ks] = *(const bf16x8*)&wlds[(mt * 16 + m) * 128 + (((ks * 4 + qq) ^ m) * 8)];
    f32x4 acc = {0.f, 0.f, 0.f, 0.f};
    #pragma unroll
    for (int ks = 0; ks < 4; ++ks)
      acc = __builtin_amdgcn_mfma_f32_16x16x32_bf16(afrag[ks], bfrag[ks], acc, 0, 0, 0);
    const int hw = ntg * 16 + m;
    #pragma unroll
    for (int r = 0; r < 4; ++r) {
      const int d = mt * 16 + qq * 4 + r;
      out[((size_t)bs * CC + d) * HWN + hw] = acc[r] + bout[d];
    }
  }
}

extern "C" void kernel_launch(void* const* d_in, const int* in_sizes, int n_in,
                              void* d_out, int out_size, void* d_ws, size_t ws_size,
                              hipStream_t stream) {
  const float* seq  = (const float*)d_in[0];
  const float* wqkv = (const float*)d_in[1];
  const float* wout = (const float*)d_in[2];
  const float* bout = (const float*)d_in[3];
  char* ws = (char*)d_ws;
  // ws layout (bytes): wqkv_b 98304 | wout_b 32768 | qkvh 100663296 | attn 147456
  ushort* wqkv_b = (ushort*)(ws);
  ushort* wout_b = (ushort*)(ws + 98304);
  ushort* qkvh   = (ushort*)(ws + 131072);
  float*  attn   = (float*)(ws + 131072 + 100663296ull);
  float*  outp   = (float*)d_out;

  hipLaunchKernelGGL(k_convert, dim3(192),  dim3(256), 0, stream, wqkv, wout, wqkv_b, wout_b);
  hipLaunchKernelGGL(k_qkv,     dim3(1536), dim3(256), 0, stream, seq, wqkv_b, qkvh);
  hipLaunchKernelGGL(k_scores,  dim3(256),  dim3(1024), 0, stream, qkvh, attn);
  hipLaunchKernelGGL(k_out,     dim3(2048), dim3(256), 0, stream, qkvh, attn, wout_b, bout, outp);
}

// Round 6
// 190.031 us; speedup vs baseline: 1.4858x; 1.1204x over previous
//
#include <hip/hip_runtime.h>

#define BATCH 2
#define SS    256   // 16x16 subdomain grid
#define CC    128
#define HWN   256   // 16x16 spatial
#define FDIM  4096  // 64 ch * 8 * 8 per head

typedef unsigned int uint;
typedef unsigned short ushort;
typedef short bf16x8 __attribute__((ext_vector_type(8)));
typedef ushort us4 __attribute__((ext_vector_type(4)));
typedef float f32x4 __attribute__((ext_vector_type(4)));

__device__ __forceinline__ ushort f2b(float f) {
  uint u = __float_as_uint(f);
  return (ushort)((u + 0x7fffu + ((u >> 16) & 1u)) >> 16);  // RNE
}
__device__ __forceinline__ float b2f(ushort h) { return __uint_as_float((uint)h << 16); }

// ---------------- K0: convert weights to bf16 (wout permuted to cc' order) ---
__global__ void k_convert(const float* __restrict__ wqkv, const float* __restrict__ wout,
                          ushort* __restrict__ wqkv_b, ushort* __restrict__ wout_b) {
  int i = blockIdx.x * 256 + threadIdx.x;
  if (i < 384 * 128) wqkv_b[i] = f2b(wqkv[i]);
  if (i < 128 * 128) {
    const int cc = i & 127;
    const int ks = cc >> 5, qq = (cc >> 3) & 3, j = cc & 7;
    const int creal = (ks >> 1) * 64 + ((((ks & 1) << 1) | (qq >> 1)) << 4)
                      + ((qq & 1) << 3) + j;
    wout_b[i] = f2b(wout[(i >> 7) * 128 + creal]);
  }
}

// ---------------- K1: qkv projection, all 3 qkvi per block ----------------
// Grid: 512 bs x 4 hq, 256 threads (4 waves, 1 ntg each). seq read ONCE.
// Weight slices staged into one 32 KB LDS buffer sequentially (3 phases).
// Unified layout: qkvh[(qkvi*16+b*8+n)][s][f'], f' = (c>>4)*1024 + hwl*16 + (c&15)
__global__ __launch_bounds__(256) void k_qkv(const float* __restrict__ seq,
                                             const ushort* __restrict__ wqkv_b,
                                             ushort* __restrict__ qkvh) {
  __shared__ ushort wlds[128 * 128];   // 32 KB, XOR-swizzled 16-B blocks
  const int blk = blockIdx.x;
  const int bs = blk >> 2, hq = blk & 3;
  const int b = bs >> 8, s = bs & 255;
  const int t = threadIdx.x;
  const int wave = t >> 6, lane = t & 63;
  const int qq = lane >> 4, m = lane & 15;
  const int ntg = hq * 4 + wave;          // this wave's hw row (0..15)
  const int hw = ntg * 16 + m;

  const float* sp = seq + (size_t)bs * (CC * HWN);

  // B fragment: bfrag[ks] elem j = bf16(seq[c=ks*32+qq*8+j][hw])
  bf16x8 bfrag[4];
  #pragma unroll
  for (int ks = 0; ks < 4; ++ks) {
    const int k0 = ks * 32 + qq * 8;
    float tmp[8];
    #pragma unroll
    for (int j = 0; j < 8; ++j) tmp[j] = sp[(k0 + j) * HWN + hw];
    bf16x8 fr;
    #pragma unroll
    for (int j = 0; j < 8; ++j) fr[j] = (short)f2b(tmp[j]);
    bfrag[ks] = fr;
  }

  const int n_qk = ((ntg >> 3) * 2 + (m >> 3)) * 2;     // head base (+ch)
  const int hwl  = (ntg & 7) * 8 + (m & 7);             // local spatial idx

  for (int qkvi = 0; qkvi < 3; ++qkvi) {
    if (qkvi > 0) __syncthreads();   // previous phase's LDS reads done
    // Stage this qkvi's 128x128 weight slice into LDS, coalesced.
    #pragma unroll
    for (int i = 0; i < 8; ++i) {
      const int row = i * 16 + (t >> 4), col16 = t & 15;
      bf16x8 w = *(const bf16x8*)(wqkv_b + (qkvi * 128 + row) * 128 + col16 * 8);
      *(bf16x8*)&wlds[row * 128 + ((col16 ^ (row & 15)) * 8)] = w;
    }
    __syncthreads();

    #pragma unroll
    for (int mt8 = 0; mt8 < 8; ++mt8) {
      bf16x8 afrag[4];
      #pragma unroll
      for (int ks = 0; ks < 4; ++ks)
        afrag[ks] = *(const bf16x8*)&wlds[(mt8 * 16 + m) * 128 + (((ks * 4 + qq) ^ m) * 8)];
      const int ch = mt8 >> 2, m4 = mt8 & 3;
      f32x4 acc = {0.f, 0.f, 0.f, 0.f};
      #pragma unroll
      for (int ks = 0; ks < 4; ++ks)
        acc = __builtin_amdgcn_mfma_f32_16x16x32_bf16(afrag[ks], bfrag[ks], acc, 0, 0, 0);
      const int n = n_qk + ch;
      const size_t base = ((size_t)(qkvi * 16 + b * 8 + n) * SS + s) * FDIM;
      us4 pk;
      #pragma unroll
      for (int r = 0; r < 4; ++r) pk[r] = f2b(acc[r]);
      *(us4*)(qkvh + base + m4 * 1024 + hwl * 16 + qq * 4) = pk;
    }
  }
}

// ---------------- K2: MFMA scores + softmax -> <=9 weights per (b,n,s) -------
// Block = (b,n,sy), XCD-swizzled so each XCD owns 2 whole (b,n) slices.
__global__ __launch_bounds__(1024) void k_scores(const ushort* __restrict__ qkvh,
                                                 float* __restrict__ attn) {
  __shared__ float red[16][64][12];
  const int g = blockIdx.x;
  const int unit = (g & 7) * 32 + (g >> 3);   // XCD swizzle
  const int b  = unit >> 7;
  const int n  = (unit >> 4) & 7;
  const int sy = unit & 15;
  const int t = threadIdx.x;
  const int wave = t >> 6, lane = t & 63;
  const int qq = lane >> 4, l15 = lane & 15;
  const size_t hs = (size_t)SS * FDIM;
  const ushort* qb = qkvh + (size_t)(b * 8 + n) * hs;
  const ushort* kb = qkvh + (size_t)(16 + b * 8 + n) * hs;

  const ushort* qp = qb + (size_t)(sy * 16 + l15) * FDIM + qq * 8;
  const ushort* kp[3];
  #pragma unroll
  for (int tl = 0; tl < 3; ++tl) {
    const int tyc = min(max(sy - 1 + tl, 0), 15);
    kp[tl] = kb + (size_t)(tyc * 16 + l15) * FDIM + qq * 8;
  }

  f32x4 acc[3] = {{0,0,0,0},{0,0,0,0},{0,0,0,0}};
  const int kbeg = wave * 256;
  #pragma unroll
  for (int it = 0; it < 4; ++it) {
    const int k0 = kbeg + it * 64;
    bf16x8 a0 = *(const bf16x8*)(qp + k0);
    bf16x8 a1 = *(const bf16x8*)(qp + k0 + 32);
    bf16x8 b0[3], b1[3];
    #pragma unroll
    for (int tl = 0; tl < 3; ++tl) {
      b0[tl] = *(const bf16x8*)(kp[tl] + k0);
      b1[tl] = *(const bf16x8*)(kp[tl] + k0 + 32);
    }
    #pragma unroll
    for (int tl = 0; tl < 3; ++tl)
      acc[tl] = __builtin_amdgcn_mfma_f32_16x16x32_bf16(a0, b0[tl], acc[tl], 0, 0, 0);
    #pragma unroll
    for (int tl = 0; tl < 3; ++tl)
      acc[tl] = __builtin_amdgcn_mfma_f32_16x16x32_bf16(a1, b1[tl], acc[tl], 0, 0, 0);
  }

  #pragma unroll
  for (int tl = 0; tl < 3; ++tl)
    #pragma unroll
    for (int r = 0; r < 4; ++r) red[wave][lane][tl * 4 + r] = acc[tl][r];
  __syncthreads();
  if (t < 768) {
    const int lane2 = t / 12, idx = t - lane2 * 12;
    float ssum = red[0][lane2][idx];
    #pragma unroll
    for (int w = 1; w < 16; ++w) ssum += red[w][lane2][idx];
    red[0][lane2][idx] = ssum;
  }
  __syncthreads();
  if (wave != 0) return;
  #pragma unroll
  for (int tl = 0; tl < 3; ++tl)
    #pragma unroll
    for (int r = 0; r < 4; ++r) acc[tl][r] = red[0][lane][tl * 4 + r];

  // mask + softmax.  D layout: row sx = qq*4+r, col tx = l15.
  const int tx = l15;
  float sc[3][4];
  #pragma unroll
  for (int tl = 0; tl < 3; ++tl) {
    const int ty = sy - 1 + tl;
    const bool tyv = (ty >= 0 && ty < 16);
    #pragma unroll
    for (int r = 0; r < 4; ++r) {
      const int sx = qq * 4 + r;
      const bool v = tyv && (tx - sx <= 1) && (sx - tx <= 1);
      sc[tl][r] = v ? acc[tl][r] * (1.f / 64.f) : -1e30f;
    }
  }
  #pragma unroll
  for (int r = 0; r < 4; ++r) {
    float mx = fmaxf(fmaxf(sc[0][r], sc[1][r]), sc[2][r]);
    #pragma unroll
    for (int off = 1; off < 16; off <<= 1) mx = fmaxf(mx, __shfl_xor(mx, off));
    float p[3], sum = 0.f;
    #pragma unroll
    for (int tl = 0; tl < 3; ++tl) { p[tl] = __expf(sc[tl][r] - mx); sum += p[tl]; }
    #pragma unroll
    for (int off = 1; off < 16; off <<= 1) sum += __shfl_xor(sum, off);
    const float inv = 1.f / sum;
    const int sx = qq * 4 + r;
    const int s = sy * 16 + sx;
    #pragma unroll
    for (int tl = 0; tl < 3; ++tl) {
      const int ty = sy - 1 + tl;
      const int dxp = tx - sx + 1;
      if (ty >= 0 && ty < 16 && dxp >= 0 && dxp <= 2)
        attn[((size_t)(b * 8 + n) * SS + s) * 9 + tl * 3 + dxp] = p[tl] * inv;
    }
  }
}

// ---------------- K3: PV + out projection, XCD-swizzled ----------------------
// Each XCD owns whole (b,sy) regions -> 3-row v working set stays in its L2.
__global__ __launch_bounds__(256) void k_out(const ushort* __restrict__ qkvh,
                                             const float* __restrict__ attn,
                                             const ushort* __restrict__ wout_b,
                                             const float* __restrict__ bout,
                                             float* __restrict__ out) {
  __shared__ ushort wlds[128 * 128];   // 32 KB, XOR-swizzled
  const int g = blockIdx.x;
  // swizzle: XCD = g&7 owns regions G = (g&7)*4 + ((g>>3)>>6)
  const int r9 = g >> 3;
  const int G = (g & 7) * 4 + (r9 >> 6);      // (b,sy) region, 0..31
  const int idx = r9 & 63;                     // 16 sx x 4 sub
  const int b = G >> 4, sy = G & 15;
  const int sx = idx >> 2, sub = idx & 3;
  const int s = sy * 16 + sx;
  const int bs = b * 256 + s;
  const int t = threadIdx.x;
  const int wave = t >> 6, lane = t & 63;
  const int ntg = sub * 4 + wave;
  const int qq = lane >> 4, m = lane & 15;
  const size_t hs = (size_t)SS * FDIM;

  // Stage permuted wout into LDS, coalesced.
  #pragma unroll
  for (int i = 0; i < 8; ++i) {
    const int row = i * 16 + (t >> 4), col16 = t & 15;
    bf16x8 w = *(const bf16x8*)(wout_b + row * 128 + col16 * 8);
    *(bf16x8*)&wlds[row * 128 + ((col16 ^ (row & 15)) * 8)] = w;
  }

  int sjc[9];
  bool vld[9];
  #pragma unroll
  for (int j = 0; j < 9; ++j) {
    const int ny = sy + j / 3 - 1, nx = sx + j % 3 - 1;
    vld[j] = (ny >= 0 && ny < 16 && nx >= 0 && nx < 16);
    sjc[j] = min(max(ny, 0), 15) * 16 + min(max(nx, 0), 15);
  }

  const int nbase = ((ntg >> 3) * 2 + (m >> 3)) * 2;  // + ch
  float pch[2][9];
  #pragma unroll
  for (int ch = 0; ch < 2; ++ch) {
    #pragma unroll
    for (int j = 0; j < 9; ++j) {
      const float w = attn[((size_t)(b * 8 + nbase + ch) * SS + s) * 9 + j];
      pch[ch][j] = vld[j] ? w : 0.f;
    }
  }

  // sa in MFMA B-fragment layout; unified v layout -> 4 x 256-B segments/load
  const int hwl = (ntg & 7) * 8 + (m & 7);
  bf16x8 bfrag[4];
  #pragma unroll
  for (int ks = 0; ks < 4; ++ks) {
    const int ch = ks >> 1;
    const int c64hi = ((ks & 1) << 1) | (qq >> 1);
    const int half = qq & 1;
    const ushort* vb = qkvh + (size_t)(32 + b * 8 + nbase + ch) * hs;
    const int off = c64hi * 1024 + hwl * 16 + half * 8;
    float facc[8] = {0.f, 0.f, 0.f, 0.f, 0.f, 0.f, 0.f, 0.f};
    #pragma unroll
    for (int j = 0; j < 9; ++j) {
      bf16x8 vv = *(const bf16x8*)(vb + (size_t)sjc[j] * FDIM + off);
      const float pj = pch[ch][j];
      #pragma unroll
      for (int e = 0; e < 8; ++e) facc[e] += pj * b2f((ushort)vv[e]);
    }
    bf16x8 fr;
    #pragma unroll
    for (int e = 0; e < 8; ++e) fr[e] = (short)f2b(facc[e]);
    bfrag[ks] = fr;
  }

  __syncthreads();   // staging complete before afrag reads

  // out[d][hw] = wout_perm[d][cc'] @ sa[cc'][hw] + bout[d]
  #pragma unroll
  for (int mt = 0; mt < 8; ++mt) {
    bf16x8 afrag[4];
    #pragma unroll
    for (int ks = 0; ks < 4; ++ks)
      afrag[ks] = *(const bf16x8*)&wlds[(mt * 16 + m) * 128 + (((ks * 4 + qq) ^ m) * 8)];
    f32x4 acc = {0.f, 0.f, 0.f, 0.f};
    #pragma unroll
    for (int ks = 0; ks < 4; ++ks)
      acc = __builtin_amdgcn_mfma_f32_16x16x32_bf16(afrag[ks], bfrag[ks], acc, 0, 0, 0);
    const int hw = ntg * 16 + m;
    #pragma unroll
    for (int r = 0; r < 4; ++r) {
      const int d = mt * 16 + qq * 4 + r;
      out[((size_t)bs * CC + d) * HWN + hw] = acc[r] + bout[d];
    }
  }
}

extern "C" void kernel_launch(void* const* d_in, const int* in_sizes, int n_in,
                              void* d_out, int out_size, void* d_ws, size_t ws_size,
                              hipStream_t stream) {
  const float* seq  = (const float*)d_in[0];
  const float* wqkv = (const float*)d_in[1];
  const float* wout = (const float*)d_in[2];
  const float* bout = (const float*)d_in[3];
  char* ws = (char*)d_ws;
  // ws layout (bytes): wqkv_b 98304 | wout_b 32768 | qkvh 100663296 | attn 147456
  ushort* wqkv_b = (ushort*)(ws);
  ushort* wout_b = (ushort*)(ws + 98304);
  ushort* qkvh   = (ushort*)(ws + 131072);
  float*  attn   = (float*)(ws + 131072 + 100663296ull);
  float*  outp   = (float*)d_out;

  hipLaunchKernelGGL(k_convert, dim3(192),  dim3(256), 0, stream, wqkv, wout, wqkv_b, wout_b);
  hipLaunchKernelGGL(k_qkv,     dim3(2048), dim3(256), 0, stream, seq, wqkv_b, qkvh);
  hipLaunchKernelGGL(k_scores,  dim3(256),  dim3(1024), 0, stream, qkvh, attn);
  hipLaunchKernelGGL(k_out,     dim3(2048), dim3(256), 0, stream, qkvh, attn, wout_b, bout, outp);
}